// Round 2
// baseline (375.222 us; speedup 1.0000x reference)
//
#include <hip/hip_runtime.h>
#include <hip/hip_bf16.h>
#include <stdint.h>

typedef __bf16 bf16;
typedef __bf16 bf16x8 __attribute__((ext_vector_type(8)));
typedef float f32x4 __attribute__((ext_vector_type(4)));
typedef unsigned short u16;
typedef unsigned int u32;

__device__ static inline u16 f2bf_bits(float f) {
    __bf16 b = (__bf16)f;
    return __builtin_bit_cast(u16, b);
}

typedef __attribute__((address_space(1))) const u32 gl_u32;
typedef __attribute__((address_space(3))) u32 lo_u32;

// async global->LDS, 16B per lane; LDS dest = wave-uniform base + lane*16
__device__ static inline void gload_lds16(const void* gp, void* lp) {
    __builtin_amdgcn_global_load_lds((gl_u32*)gp, (lo_u32*)lp, 16, 0, 0);
}

// ---------------------------------------------------------------------------
// fp32 -> bf16 conversion (vectorized)
// ---------------------------------------------------------------------------
__global__ void cvt_f32_to_bf16(const float* __restrict__ in, u16* __restrict__ out, int n4) {
    int i = blockIdx.x * blockDim.x + threadIdx.x;
    if (i >= n4) return;
    float4 f = ((const float4*)in)[i];
    ushort4 o;
    o.x = f2bf_bits(f.x);
    o.y = f2bf_bits(f.y);
    o.z = f2bf_bits(f.z);
    o.w = f2bf_bits(f.w);
    ((ushort4*)out)[i] = o;
}

// ---------------------------------------------------------------------------
// m97-style 128x128x32 GEMM: C = A @ W^T + bias
// A: [8192][1024] bf16 row-major, W: [1024][1024] bf16 row-major
// MODE 0: out bf16 [B=4][H=16][S=2048][DK=64]   (Q/K layout)
// MODE 1: out bf16 [B][H][DK][S]                (V transposed)
// MODE 2: out fp32 [8192][1024]                 (final projection)
// ---------------------------------------------------------------------------
template <int MODE>
__global__ __launch_bounds__(256) void gemm_bt(const bf16* __restrict__ A,
                                               const bf16* __restrict__ W,
                                               const float* __restrict__ bias,
                                               void* __restrict__ Out) {
    constexpr int K = 1024;
    __shared__ unsigned char As[8192];
    __shared__ unsigned char Bs[8192];

    const int tid = threadIdx.x;
    const int lane = tid & 63, w = tid >> 6;
    const int l15 = lane & 15, l4 = lane >> 4;
    const int wr = w >> 1, wc = w & 1;
    const int bid = blockIdx.x;
    const int bm = bid >> 3, bn = bid & 7;
    const int m0 = bm * 128, n0 = bn * 128;

    f32x4 acc[4][4] = {};

    int aoff[4], boff[4];
#pragma unroll
    for (int i = 0; i < 4; ++i) {
        aoff[i] = (wr * 64 + i * 16 + l15) * 64 + l4 * 16;
        boff[i] = (wc * 64 + i * 16 + l15) * 64 + l4 * 16;
    }

    const int c0 = tid, c1 = 256 + tid;
    const int ar0 = m0 + (c0 >> 2), ar1 = m0 + (c1 >> 2);
    const int br0 = n0 + (c0 >> 2), br1 = n0 + (c1 >> 2);
    const int sl0 = (c0 & 3) * 8, sl1 = (c1 & 3) * 8;

    for (int k0 = 0; k0 < K; k0 += 32) {
        __syncthreads();
        gload_lds16(A + (size_t)ar0 * K + k0 + sl0, As + w * 1024);
        gload_lds16(A + (size_t)ar1 * K + k0 + sl1, As + 4096 + w * 1024);
        gload_lds16(W + (size_t)br0 * K + k0 + sl0, Bs + w * 1024);
        gload_lds16(W + (size_t)br1 * K + k0 + sl1, Bs + 4096 + w * 1024);
        __syncthreads();
        bf16x8 af[4], bfr[4];
#pragma unroll
        for (int i = 0; i < 4; ++i) af[i] = *(const bf16x8*)(As + aoff[i]);
#pragma unroll
        for (int i = 0; i < 4; ++i) bfr[i] = *(const bf16x8*)(Bs + boff[i]);
#pragma unroll
        for (int mi = 0; mi < 4; ++mi)
#pragma unroll
            for (int ni = 0; ni < 4; ++ni)
                acc[mi][ni] = __builtin_amdgcn_mfma_f32_16x16x32_bf16(af[mi], bfr[ni], acc[mi][ni], 0, 0, 0);
    }

    // epilogue: m = m0 + wr*64 + mi*16 + l4*4 + r ; n = n0 + wc*64 + ni*16 + l15
#pragma unroll
    for (int mi = 0; mi < 4; ++mi) {
        const int mb = m0 + wr * 64 + mi * 16 + l4 * 4;
#pragma unroll
        for (int ni = 0; ni < 4; ++ni) {
            const int n = n0 + wc * 64 + ni * 16 + l15;
            const float bv = bias[n];
            if (MODE == 0) {
                const int hh = n >> 6, dk = n & 63;
#pragma unroll
                for (int r = 0; r < 4; ++r) {
                    const int m = mb + r;
                    const int bb = m >> 11, s = m & 2047;
                    ((u16*)Out)[(((size_t)bb * 16 + hh) * 2048 + s) * 64 + dk] =
                        f2bf_bits(acc[mi][ni][r] + bv);
                }
            } else if (MODE == 1) {
                const int hh = n >> 6, dk = n & 63;
                const int bb = mb >> 11, s = mb & 2047;
                ushort4 pk;
                pk.x = f2bf_bits(acc[mi][ni][0] + bv);
                pk.y = f2bf_bits(acc[mi][ni][1] + bv);
                pk.z = f2bf_bits(acc[mi][ni][2] + bv);
                pk.w = f2bf_bits(acc[mi][ni][3] + bv);
                *(ushort4*)((u16*)Out + (((size_t)bb * 16 + hh) * 64 + dk) * 2048 + s) = pk;
            } else {
#pragma unroll
                for (int r = 0; r < 4; ++r) {
                    const int m = mb + r;
                    ((float*)Out)[(size_t)m * 1024 + n] = acc[mi][ni][r] + bv;
                }
            }
        }
    }
}

// ---------------------------------------------------------------------------
// Flash attention: grid = B*H*(S/64) = 2048 blocks, 256 threads (4 waves).
// Q,K: [BH][S][64] bf16 ; Vt: [BH][64][S] bf16 ; mask: [B][S] int
// Out Xa: [B][S][1024] bf16  (= [B][S][H][64])
// Per wave: 16 q-rows. QK^T and PV via mfma 16x16x32; PV computed as
// O^T = V^T * P^T. K/Vt LDS tiles XOR-swizzled via pre-swizzled global src.
// ---------------------------------------------------------------------------
__global__ __launch_bounds__(256) void attn_kernel(const bf16* __restrict__ Q,
                                                   const bf16* __restrict__ Kg,
                                                   const bf16* __restrict__ Vt,
                                                   const int* __restrict__ msk,
                                                   u16* __restrict__ Xa) {
    constexpr int S = 2048;
    __shared__ unsigned char Ks[8192];
    __shared__ unsigned char Vs[8192];
    __shared__ unsigned char Ps[4][2048];
    __shared__ int mk[64];

    const int tid = threadIdx.x;
    const int lane = tid & 63, w = tid >> 6;
    const int l15 = lane & 15, l4 = lane >> 4;
    const int bid = blockIdx.x;
    const int bh = bid >> 5;  // 32 q-tiles per (b,h)
    const int qt = bid & 31;
    const int b = bh >> 4, h = bh & 15;
    const int q0 = qt * 64;

    // Q fragments, kept in registers for the whole block
    const bf16* Qrow = Q + ((size_t)bh * S + q0 + w * 16 + l15) * 64;
    bf16x8 qf[2];
    qf[0] = *(const bf16x8*)(Qrow + l4 * 8);
    qf[1] = *(const bf16x8*)(Qrow + 32 + l4 * 8);

    f32x4 oa[4] = {};
    float mrow[4], lrow[4];
#pragma unroll
    for (int r = 0; r < 4; ++r) { mrow[r] = -3.0e38f; lrow[r] = 0.f; }

    const bf16* Kbh = Kg + (size_t)bh * S * 64;
    const bf16* Vbh = Vt + (size_t)bh * 64 * S;
    const int* mb = msk + b * S;

    const int srcl = (l15 >> 2) * 16;
    const int rq = l15 & 3;

    for (int kt = 0; kt < S / 64; ++kt) {
        const int k0 = kt * 64;
        __syncthreads();
#pragma unroll
        for (int p = 0; p < 2; ++p) {
            const int c = p * 256 + tid;
            const int row = c >> 3;
            const int gsl = (c & 7) ^ (row & 7);  // pre-swizzled source chunk
            gload_lds16(Kbh + (size_t)(k0 + row) * 64 + gsl * 8, Ks + p * 4096 + w * 1024);
            gload_lds16(Vbh + (size_t)row * S + k0 + gsl * 8, Vs + p * 4096 + w * 1024);
        }
        if (tid < 64) mk[tid] = mb[k0 + tid];
        __syncthreads();

        // ---- QK^T ----
        f32x4 sa[4] = {};
#pragma unroll
        for (int ni = 0; ni < 4; ++ni) {
            const int n = ni * 16 + l15;
#pragma unroll
            for (int kc = 0; kc < 2; ++kc) {
                bf16x8 kf = *(const bf16x8*)(Ks + n * 128 + (((kc * 4 + l4) ^ (n & 7)) << 4));
                sa[ni] = __builtin_amdgcn_mfma_f32_16x16x32_bf16(qf[kc], kf, sa[ni], 0, 0, 0);
            }
        }

        // ---- scale + mask ----
        float sv[4][4];
#pragma unroll
        for (int ni = 0; ni < 4; ++ni) {
            const int km = mk[ni * 16 + l15];
#pragma unroll
            for (int r = 0; r < 4; ++r)
                sv[ni][r] = km ? sa[ni][r] * 0.125f : -1.0e9f;
        }

        // ---- online softmax (row = l4*4 + r within wave's 16 rows) ----
        float rmax[4];
#pragma unroll
        for (int r = 0; r < 4; ++r)
            rmax[r] = fmaxf(fmaxf(sv[0][r], sv[1][r]), fmaxf(sv[2][r], sv[3][r]));
#pragma unroll
        for (int off = 1; off < 16; off <<= 1)
#pragma unroll
            for (int r = 0; r < 4; ++r)
                rmax[r] = fmaxf(rmax[r], __shfl_xor(rmax[r], off));

        float mnew[4], al[4], psum[4];
#pragma unroll
        for (int r = 0; r < 4; ++r) {
            mnew[r] = fmaxf(mrow[r], rmax[r]);
            al[r] = __expf(mrow[r] - mnew[r]);
            psum[r] = 0.f;
        }

        // p = exp(s - m_new); write P (bf16) to swizzled LDS
#pragma unroll
        for (int ni = 0; ni < 4; ++ni) {
            const int k = ni * 16 + l15;
#pragma unroll
            for (int r = 0; r < 4; ++r) {
                const float p = __expf(sv[ni][r] - mnew[r]);
                psum[r] += p;
                const int qq = l4 * 4 + r;
                *(u16*)(&Ps[w][qq * 128 + (((k >> 3) ^ (qq & 7)) << 4) + ((k & 7) << 1)]) =
                    f2bf_bits(p);
            }
        }
#pragma unroll
        for (int off = 1; off < 16; off <<= 1)
#pragma unroll
            for (int r = 0; r < 4; ++r)
                psum[r] += __shfl_xor(psum[r], off);
#pragma unroll
        for (int r = 0; r < 4; ++r) {
            lrow[r] = lrow[r] * al[r] + psum[r];
            mrow[r] = mnew[r];
        }

        // transpose alpha into O^T layout (q = l15)
        const float a0 = __shfl(al[0], srcl);
        const float a1 = __shfl(al[1], srcl);
        const float a2 = __shfl(al[2], srcl);
        const float a3 = __shfl(al[3], srcl);
        const float aq = (rq == 0) ? a0 : (rq == 1) ? a1 : (rq == 2) ? a2 : a3;
#pragma unroll
        for (int df = 0; df < 4; ++df) oa[df] = oa[df] * aq;

        // ---- PV: O^T += V^T * P^T ----
#pragma unroll
        for (int kc = 0; kc < 2; ++kc) {
            bf16x8 pf = *(const bf16x8*)(&Ps[w][l15 * 128 + ((((kc << 2) | l4) ^ (l15 & 7)) << 4)]);
#pragma unroll
            for (int df = 0; df < 4; ++df) {
                const int d = df * 16 + l15;
                bf16x8 vf = *(const bf16x8*)(Vs + d * 128 + ((((kc << 2) | l4) ^ (d & 7)) << 4));
                oa[df] = __builtin_amdgcn_mfma_f32_16x16x32_bf16(vf, pf, oa[df], 0, 0, 0);
            }
        }
    }

    // ---- finalize: divide by row sums, store [B][S][H*64] bf16 ----
    const float l0 = __shfl(lrow[0], srcl);
    const float l1 = __shfl(lrow[1], srcl);
    const float l2 = __shfl(lrow[2], srcl);
    const float l3 = __shfl(lrow[3], srcl);
    const float lq = (rq == 0) ? l0 : (rq == 1) ? l1 : (rq == 2) ? l2 : l3;
    const float inv = 1.0f / lq;

    const size_t orow = ((size_t)(b * 2048 + q0 + w * 16 + l15)) * 1024 + h * 64;
#pragma unroll
    for (int df = 0; df < 4; ++df) {
        ushort4 pk;
        pk.x = f2bf_bits(oa[df][0] * inv);
        pk.y = f2bf_bits(oa[df][1] * inv);
        pk.z = f2bf_bits(oa[df][2] * inv);
        pk.w = f2bf_bits(oa[df][3] * inv);
        *(ushort4*)(Xa + orow + df * 16 + l4 * 4) = pk;
    }
}

// ---------------------------------------------------------------------------
extern "C" void kernel_launch(void* const* d_in, const int* in_sizes, int n_in,
                              void* d_out, int out_size, void* d_ws, size_t ws_size,
                              hipStream_t stream) {
    const float* q_in = (const float*)d_in[0];
    const float* k_in = (const float*)d_in[1];
    const float* v_in = (const float*)d_in[2];
    const int* msk    = (const int*)d_in[3];
    const float* Wq = (const float*)d_in[4];
    const float* bq = (const float*)d_in[5];
    const float* Wk = (const float*)d_in[6];
    const float* bk = (const float*)d_in[7];
    const float* Wv = (const float*)d_in[8];
    const float* bv = (const float*)d_in[9];
    const float* Wo = (const float*)d_in[10];
    const float* bo = (const float*)d_in[11];

    char* ws = (char*)d_ws;
    const size_t MB = 1024ull * 1024ull;
    u16* xq  = (u16*)(ws + 0 * MB);    // 16 MB
    u16* xk  = (u16*)(ws + 16 * MB);   // 16 MB
    u16* xv  = (u16*)(ws + 32 * MB);   // 16 MB
    u16* wqb = (u16*)(ws + 48 * MB);   // 2 MB
    u16* wkb = (u16*)(ws + 50 * MB);
    u16* wvb = (u16*)(ws + 52 * MB);
    u16* wob = (u16*)(ws + 54 * MB);
    u16* Qb  = (u16*)(ws + 56 * MB);   // 16 MB  [B,H,S,64]
    u16* Kb  = (u16*)(ws + 72 * MB);   // 16 MB  [B,H,S,64]
    u16* Vtb = (u16*)(ws + 88 * MB);   // 16 MB  [B,H,64,S]
    u16* Xa  = (u16*)(ws + 0 * MB);    // reuse xq region after Q-GEMM

    const int nbig4 = (4 * 2048 * 1024) / 4;  // 2,097,152
    const int nw4 = (1024 * 1024) / 4;        // 262,144

    cvt_f32_to_bf16<<<dim3((nbig4 + 255) / 256), dim3(256), 0, stream>>>(q_in, xq, nbig4);
    cvt_f32_to_bf16<<<dim3((nbig4 + 255) / 256), dim3(256), 0, stream>>>(k_in, xk, nbig4);
    cvt_f32_to_bf16<<<dim3((nbig4 + 255) / 256), dim3(256), 0, stream>>>(v_in, xv, nbig4);
    cvt_f32_to_bf16<<<dim3((nw4 + 255) / 256), dim3(256), 0, stream>>>(Wq, wqb, nw4);
    cvt_f32_to_bf16<<<dim3((nw4 + 255) / 256), dim3(256), 0, stream>>>(Wk, wkb, nw4);
    cvt_f32_to_bf16<<<dim3((nw4 + 255) / 256), dim3(256), 0, stream>>>(Wv, wvb, nw4);
    cvt_f32_to_bf16<<<dim3((nw4 + 255) / 256), dim3(256), 0, stream>>>(Wo, wob, nw4);

    gemm_bt<0><<<dim3(512), dim3(256), 0, stream>>>((const bf16*)xq, (const bf16*)wqb, bq, (void*)Qb);
    gemm_bt<0><<<dim3(512), dim3(256), 0, stream>>>((const bf16*)xk, (const bf16*)wkb, bk, (void*)Kb);
    gemm_bt<1><<<dim3(512), dim3(256), 0, stream>>>((const bf16*)xv, (const bf16*)wvb, bv, (void*)Vtb);

    attn_kernel<<<dim3(2048), dim3(256), 0, stream>>>((const bf16*)Qb, (const bf16*)Kb,
                                                      (const bf16*)Vtb, msk, Xa);

    gemm_bt<2><<<dim3(512), dim3(256), 0, stream>>>((const bf16*)Xa, (const bf16*)wob, bo, d_out);
}

// Round 3
// 371.851 us; speedup vs baseline: 1.0091x; 1.0091x over previous
//
#include <hip/hip_runtime.h>
#include <hip/hip_bf16.h>
#include <stdint.h>

typedef __bf16 bf16;
typedef __bf16 bf16x8 __attribute__((ext_vector_type(8)));
typedef float f32x4 __attribute__((ext_vector_type(4)));
typedef unsigned short u16;
typedef unsigned int u32;

__device__ static inline u16 f2bf_bits(float f) {
    __bf16 b = (__bf16)f;
    return __builtin_bit_cast(u16, b);
}

typedef __attribute__((address_space(1))) const u32 gl_u32;
typedef __attribute__((address_space(3))) u32 lo_u32;

// async global->LDS, 16B per lane; LDS dest = wave-uniform base + lane*16
__device__ static inline void gload_lds16(const void* gp, void* lp) {
    __builtin_amdgcn_global_load_lds((gl_u32*)gp, (lo_u32*)lp, 16, 0, 0);
}

// ---------------------------------------------------------------------------
// fp32 -> bf16 conversion (vectorized)
// ---------------------------------------------------------------------------
__global__ void cvt_f32_to_bf16(const float* __restrict__ in, u16* __restrict__ out, int n4) {
    int i = blockIdx.x * blockDim.x + threadIdx.x;
    if (i >= n4) return;
    float4 f = ((const float4*)in)[i];
    ushort4 o;
    o.x = f2bf_bits(f.x);
    o.y = f2bf_bits(f.y);
    o.z = f2bf_bits(f.z);
    o.w = f2bf_bits(f.w);
    ((ushort4*)out)[i] = o;
}

// ---------------------------------------------------------------------------
// m97-style 128x128x32 GEMM: C = A @ W^T + bias
// A: [8192][1024] bf16 row-major, W: [1024][1024] bf16 row-major
// MODE 0: out bf16 [B=4][H=16][S=2048][DK=64]   (Q/K layout)
// MODE 1: out bf16 [B][H][DK][S]                (V transposed)
// MODE 2: out fp32 [8192][1024]                 (final projection)
// ---------------------------------------------------------------------------
template <int MODE>
__global__ __launch_bounds__(256) void gemm_bt(const bf16* __restrict__ A,
                                               const bf16* __restrict__ W,
                                               const float* __restrict__ bias,
                                               void* __restrict__ Out) {
    constexpr int K = 1024;
    __shared__ unsigned char As[8192];
    __shared__ unsigned char Bs[8192];

    const int tid = threadIdx.x;
    const int lane = tid & 63, w = tid >> 6;
    const int l15 = lane & 15, l4 = lane >> 4;
    const int wr = w >> 1, wc = w & 1;
    const int bid = blockIdx.x;
    const int bm = bid >> 3, bn = bid & 7;
    const int m0 = bm * 128, n0 = bn * 128;

    f32x4 acc[4][4] = {};

    int aoff[4], boff[4];
#pragma unroll
    for (int i = 0; i < 4; ++i) {
        aoff[i] = (wr * 64 + i * 16 + l15) * 64 + l4 * 16;
        boff[i] = (wc * 64 + i * 16 + l15) * 64 + l4 * 16;
    }

    const int c0 = tid, c1 = 256 + tid;
    const int ar0 = m0 + (c0 >> 2), ar1 = m0 + (c1 >> 2);
    const int br0 = n0 + (c0 >> 2), br1 = n0 + (c1 >> 2);
    const int sl0 = (c0 & 3) * 8, sl1 = (c1 & 3) * 8;

    for (int k0 = 0; k0 < K; k0 += 32) {
        __syncthreads();
        gload_lds16(A + (size_t)ar0 * K + k0 + sl0, As + w * 1024);
        gload_lds16(A + (size_t)ar1 * K + k0 + sl1, As + 4096 + w * 1024);
        gload_lds16(W + (size_t)br0 * K + k0 + sl0, Bs + w * 1024);
        gload_lds16(W + (size_t)br1 * K + k0 + sl1, Bs + 4096 + w * 1024);
        __syncthreads();
        bf16x8 af[4], bfr[4];
#pragma unroll
        for (int i = 0; i < 4; ++i) af[i] = *(const bf16x8*)(As + aoff[i]);
#pragma unroll
        for (int i = 0; i < 4; ++i) bfr[i] = *(const bf16x8*)(Bs + boff[i]);
#pragma unroll
        for (int mi = 0; mi < 4; ++mi)
#pragma unroll
            for (int ni = 0; ni < 4; ++ni)
                acc[mi][ni] = __builtin_amdgcn_mfma_f32_16x16x32_bf16(af[mi], bfr[ni], acc[mi][ni], 0, 0, 0);
    }

    // epilogue: m = m0 + wr*64 + mi*16 + l4*4 + r ; n = n0 + wc*64 + ni*16 + l15
#pragma unroll
    for (int mi = 0; mi < 4; ++mi) {
        const int mb = m0 + wr * 64 + mi * 16 + l4 * 4;
#pragma unroll
        for (int ni = 0; ni < 4; ++ni) {
            const int n = n0 + wc * 64 + ni * 16 + l15;
            const float bv = bias[n];
            if (MODE == 0) {
                const int hh = n >> 6, dk = n & 63;
#pragma unroll
                for (int r = 0; r < 4; ++r) {
                    const int m = mb + r;
                    const int bb = m >> 11, s = m & 2047;
                    ((u16*)Out)[(((size_t)bb * 16 + hh) * 2048 + s) * 64 + dk] =
                        f2bf_bits(acc[mi][ni][r] + bv);
                }
            } else if (MODE == 1) {
                const int hh = n >> 6, dk = n & 63;
                const int bb = mb >> 11, s = mb & 2047;
                ushort4 pk;
                pk.x = f2bf_bits(acc[mi][ni][0] + bv);
                pk.y = f2bf_bits(acc[mi][ni][1] + bv);
                pk.z = f2bf_bits(acc[mi][ni][2] + bv);
                pk.w = f2bf_bits(acc[mi][ni][3] + bv);
                *(ushort4*)((u16*)Out + (((size_t)bb * 16 + hh) * 64 + dk) * 2048 + s) = pk;
            } else {
#pragma unroll
                for (int r = 0; r < 4; ++r) {
                    const int m = mb + r;
                    ((float*)Out)[(size_t)m * 1024 + n] = acc[mi][ni][r] + bv;
                }
            }
        }
    }
}

// ---------------------------------------------------------------------------
// Flash attention: grid = B*H*(S/64) = 2048 blocks, 256 threads (4 waves).
// Q,K: [BH][S][64] bf16 ; Vt: [BH][64][S] bf16 ; mask: [B][S] int
// Out Xa: [B][S][1024] bf16  (= [B][S][H][64])
// Per wave: 16 q-rows. QK^T and PV via mfma 16x16x32; PV computed as
// O^T = V^T * P^T. K/Vt LDS tiles XOR-swizzled via pre-swizzled global src.
// ---------------------------------------------------------------------------
__global__ __launch_bounds__(256) void attn_kernel(const bf16* __restrict__ Q,
                                                   const bf16* __restrict__ Kg,
                                                   const bf16* __restrict__ Vt,
                                                   const int* __restrict__ msk,
                                                   u16* __restrict__ Xa) {
    constexpr int S = 2048;
    __shared__ unsigned char Ks[8192];
    __shared__ unsigned char Vs[8192];
    __shared__ unsigned char Ps[4][2048];
    __shared__ int mk[64];

    const int tid = threadIdx.x;
    const int lane = tid & 63, w = tid >> 6;
    const int l15 = lane & 15, l4 = lane >> 4;
    const int bid = blockIdx.x;
    const int bh = bid >> 5;  // 32 q-tiles per (b,h)
    const int qt = bid & 31;
    const int b = bh >> 4, h = bh & 15;
    const int q0 = qt * 64;

    // Q fragments, kept in registers for the whole block
    const bf16* Qrow = Q + ((size_t)bh * S + q0 + w * 16 + l15) * 64;
    bf16x8 qf[2];
    qf[0] = *(const bf16x8*)(Qrow + l4 * 8);
    qf[1] = *(const bf16x8*)(Qrow + 32 + l4 * 8);

    f32x4 oa[4] = {};
    float mrow[4], lrow[4];
#pragma unroll
    for (int r = 0; r < 4; ++r) { mrow[r] = -3.0e38f; lrow[r] = 0.f; }

    const bf16* Kbh = Kg + (size_t)bh * S * 64;
    const bf16* Vbh = Vt + (size_t)bh * 64 * S;
    const int* mb = msk + b * S;

    const int srcl = (l15 >> 2) * 16;
    const int rq = l15 & 3;

    for (int kt = 0; kt < S / 64; ++kt) {
        const int k0 = kt * 64;
        __syncthreads();
#pragma unroll
        for (int p = 0; p < 2; ++p) {
            const int c = p * 256 + tid;
            const int row = c >> 3;
            const int gsl = (c & 7) ^ (row & 7);  // pre-swizzled source chunk
            gload_lds16(Kbh + (size_t)(k0 + row) * 64 + gsl * 8, Ks + p * 4096 + w * 1024);
            gload_lds16(Vbh + (size_t)row * S + k0 + gsl * 8, Vs + p * 4096 + w * 1024);
        }
        if (tid < 64) mk[tid] = mb[k0 + tid];
        __syncthreads();

        // ---- QK^T ----
        f32x4 sa[4] = {};
#pragma unroll
        for (int ni = 0; ni < 4; ++ni) {
            const int n = ni * 16 + l15;
#pragma unroll
            for (int kc = 0; kc < 2; ++kc) {
                bf16x8 kf = *(const bf16x8*)(Ks + n * 128 + (((kc * 4 + l4) ^ (n & 7)) << 4));
                sa[ni] = __builtin_amdgcn_mfma_f32_16x16x32_bf16(qf[kc], kf, sa[ni], 0, 0, 0);
            }
        }

        // ---- scale + mask ----
        float sv[4][4];
#pragma unroll
        for (int ni = 0; ni < 4; ++ni) {
            const int km = mk[ni * 16 + l15];
#pragma unroll
            for (int r = 0; r < 4; ++r)
                sv[ni][r] = km ? sa[ni][r] * 0.125f : -1.0e9f;
        }

        // ---- online softmax (row = l4*4 + r within wave's 16 rows) ----
        float rmax[4];
#pragma unroll
        for (int r = 0; r < 4; ++r)
            rmax[r] = fmaxf(fmaxf(sv[0][r], sv[1][r]), fmaxf(sv[2][r], sv[3][r]));
#pragma unroll
        for (int off = 1; off < 16; off <<= 1)
#pragma unroll
            for (int r = 0; r < 4; ++r)
                rmax[r] = fmaxf(rmax[r], __shfl_xor(rmax[r], off));

        float mnew[4], al[4], psum[4];
#pragma unroll
        for (int r = 0; r < 4; ++r) {
            mnew[r] = fmaxf(mrow[r], rmax[r]);
            al[r] = __expf(mrow[r] - mnew[r]);
            psum[r] = 0.f;
        }

        // p = exp(s - m_new); write P (bf16) to swizzled LDS
#pragma unroll
        for (int ni = 0; ni < 4; ++ni) {
            const int k = ni * 16 + l15;
#pragma unroll
            for (int r = 0; r < 4; ++r) {
                const float p = __expf(sv[ni][r] - mnew[r]);
                psum[r] += p;
                const int qq = l4 * 4 + r;
                *(u16*)(&Ps[w][qq * 128 + (((k >> 3) ^ (qq & 7)) << 4) + ((k & 7) << 1)]) =
                    f2bf_bits(p);
            }
        }
#pragma unroll
        for (int off = 1; off < 16; off <<= 1)
#pragma unroll
            for (int r = 0; r < 4; ++r)
                psum[r] += __shfl_xor(psum[r], off);
#pragma unroll
        for (int r = 0; r < 4; ++r) {
            lrow[r] = lrow[r] * al[r] + psum[r];
            mrow[r] = mnew[r];
        }

        // transpose alpha into O^T layout (q = l15)
        const float a0 = __shfl(al[0], srcl);
        const float a1 = __shfl(al[1], srcl);
        const float a2 = __shfl(al[2], srcl);
        const float a3 = __shfl(al[3], srcl);
        const float aq = (rq == 0) ? a0 : (rq == 1) ? a1 : (rq == 2) ? a2 : a3;
#pragma unroll
        for (int df = 0; df < 4; ++df) oa[df] = oa[df] * aq;

        // ---- PV: O^T += V^T * P^T ----
#pragma unroll
        for (int kc = 0; kc < 2; ++kc) {
            bf16x8 pf = *(const bf16x8*)(&Ps[w][l15 * 128 + ((((kc << 2) | l4) ^ (l15 & 7)) << 4)]);
#pragma unroll
            for (int df = 0; df < 4; ++df) {
                const int d = df * 16 + l15;
                bf16x8 vf = *(const bf16x8*)(Vs + d * 128 + ((((kc << 2) | l4) ^ (d & 7)) << 4));
                oa[df] = __builtin_amdgcn_mfma_f32_16x16x32_bf16(vf, pf, oa[df], 0, 0, 0);
            }
        }
    }

    // ---- finalize: divide by row sums, store [B][S][H*64] bf16 ----
    const float l0 = __shfl(lrow[0], srcl);
    const float l1 = __shfl(lrow[1], srcl);
    const float l2 = __shfl(lrow[2], srcl);
    const float l3 = __shfl(lrow[3], srcl);
    const float lq = (rq == 0) ? l0 : (rq == 1) ? l1 : (rq == 2) ? l2 : l3;
    const float inv = 1.0f / lq;

    const size_t orow = ((size_t)(b * 2048 + q0 + w * 16 + l15)) * 1024 + h * 64;
#pragma unroll
    for (int df = 0; df < 4; ++df) {
        ushort4 pk;
        pk.x = f2bf_bits(oa[df][0] * inv);
        pk.y = f2bf_bits(oa[df][1] * inv);
        pk.z = f2bf_bits(oa[df][2] * inv);
        pk.w = f2bf_bits(oa[df][3] * inv);
        *(ushort4*)(Xa + orow + df * 16 + l4 * 4) = pk;
    }
}

// ---------------------------------------------------------------------------
extern "C" void kernel_launch(void* const* d_in, const int* in_sizes, int n_in,
                              void* d_out, int out_size, void* d_ws, size_t ws_size,
                              hipStream_t stream) {
    const float* q_in = (const float*)d_in[0];
    const float* k_in = (const float*)d_in[1];
    const float* v_in = (const float*)d_in[2];
    const int* msk    = (const int*)d_in[3];
    const float* Wq = (const float*)d_in[4];
    const float* bq = (const float*)d_in[5];
    const float* Wk = (const float*)d_in[6];
    const float* bk = (const float*)d_in[7];
    const float* Wv = (const float*)d_in[8];
    const float* bv = (const float*)d_in[9];
    const float* Wo = (const float*)d_in[10];
    const float* bo = (const float*)d_in[11];

    char* ws = (char*)d_ws;
    const size_t MB = 1024ull * 1024ull;
    u16* xq  = (u16*)(ws + 0 * MB);    // 16 MB
    u16* xk  = (u16*)(ws + 16 * MB);   // 16 MB
    u16* xv  = (u16*)(ws + 32 * MB);   // 16 MB
    u16* wqb = (u16*)(ws + 48 * MB);   // 2 MB
    u16* wkb = (u16*)(ws + 50 * MB);
    u16* wvb = (u16*)(ws + 52 * MB);
    u16* wob = (u16*)(ws + 54 * MB);
    u16* Qb  = (u16*)(ws + 56 * MB);   // 16 MB  [B,H,S,64]
    u16* Kb  = (u16*)(ws + 72 * MB);   // 16 MB  [B,H,S,64]
    u16* Vtb = (u16*)(ws + 88 * MB);   // 16 MB  [B,H,64,S]
    u16* Xa  = (u16*)(ws + 0 * MB);    // reuse xq region after Q-GEMM

    const int nbig4 = (4 * 2048 * 1024) / 4;  // 2,097,152
    const int nw4 = (1024 * 1024) / 4;        // 262,144

    cvt_f32_to_bf16<<<dim3((nbig4 + 255) / 256), dim3(256), 0, stream>>>(q_in, xq, nbig4);
    cvt_f32_to_bf16<<<dim3((nbig4 + 255) / 256), dim3(256), 0, stream>>>(k_in, xk, nbig4);
    cvt_f32_to_bf16<<<dim3((nbig4 + 255) / 256), dim3(256), 0, stream>>>(v_in, xv, nbig4);
    cvt_f32_to_bf16<<<dim3((nw4 + 255) / 256), dim3(256), 0, stream>>>(Wq, wqb, nw4);
    cvt_f32_to_bf16<<<dim3((nw4 + 255) / 256), dim3(256), 0, stream>>>(Wk, wkb, nw4);
    cvt_f32_to_bf16<<<dim3((nw4 + 255) / 256), dim3(256), 0, stream>>>(Wv, wvb, nw4);
    cvt_f32_to_bf16<<<dim3((nw4 + 255) / 256), dim3(256), 0, stream>>>(Wo, wob, nw4);

    gemm_bt<0><<<dim3(512), dim3(256), 0, stream>>>((const bf16*)xq, (const bf16*)wqb, bq, (void*)Qb);
    gemm_bt<0><<<dim3(512), dim3(256), 0, stream>>>((const bf16*)xk, (const bf16*)wkb, bk, (void*)Kb);
    gemm_bt<1><<<dim3(512), dim3(256), 0, stream>>>((const bf16*)xv, (const bf16*)wvb, bv, (void*)Vtb);

    attn_kernel<<<dim3(2048), dim3(256), 0, stream>>>((const bf16*)Qb, (const bf16*)Kb,
                                                      (const bf16*)Vtb, msk, Xa);

    gemm_bt<2><<<dim3(512), dim3(256), 0, stream>>>((const bf16*)Xa, (const bf16*)wob, bo, d_out);
}